// Round 1
// 652.781 us; speedup vs baseline: 1.0183x; 1.0183x over previous
//
#include <hip/hip_runtime.h>
#include <hip/hip_bf16.h>

#define N_BINS 15
#define C_DIM 64

// d_ws layout: [0..14] sum_conf, [15..29] sum_acc, [30..44] count  (floats)

__global__ __launch_bounds__(256) void ece_main(const float* __restrict__ probs,
                                                const int* __restrict__ labels,
                                                float* __restrict__ gbins, int N) {
    __shared__ float s_bins[3 * N_BINS];
    const int tid = threadIdx.x;
    if (tid < 3 * N_BINS) s_bins[tid] = 0.f;
    __syncthreads();

    const int lane = tid & 63;
    const int wave = tid >> 6;
    const int l4   = lane & 3;    // which 16B sub-chunk of each 64B chunk this lane reads
    const int rsub = lane >> 2;   // which of the wave's 16 rows this lane helps
    const int wavesPerBlock = blockDim.x >> 6;

    // private accumulators (bin14 ~98.8% of rows, bin13 ~1.2%)
    float c14 = 0.f, a14 = 0.f, n14 = 0.f;
    float c13 = 0.f, a13 = 0.f, n13 = 0.f;

    // each wave handles 16 consecutive rows per iteration; 4 lanes per row
    const long long totalWaves = (long long)gridDim.x * wavesPerBlock;
    long long rowBase = ((long long)blockIdx.x * wavesPerBlock + wave) * 16;
    const long long rstride = totalWaves * 16;

    for (; rowBase < (long long)N; rowBase += rstride) {
        const long long row = rowBase + rsub;
        const bool valid = row < (long long)N;

        // lane covers columns c*16 + l4*4 + {0..3} for c = 0..3 (increasing order).
        // bytes: row*256 + c*64 + l4*16  -> for fixed c, lanes 0..3 read one full
        // contiguous 64B line of row rsub; 16 fully-consumed lines per instruction.
        float4 v0, v1, v2, v3;
        int lab = 0;
        if (valid) {
            const float* p = probs + row * 64 + l4 * 4;
            v0 = *(const float4*)(p);
            v1 = *(const float4*)(p + 16);
            v2 = *(const float4*)(p + 32);
            v3 = *(const float4*)(p + 48);
            if (l4 == 0) lab = labels[row];
        } else {
            v0 = v1 = v2 = v3 = make_float4(-1.f, -1.f, -1.f, -1.f);
        }

        // local first-occurrence argmax over this lane's 16 elements (no shuffles)
        float m;
        int a;
        {
            const int b0 = l4 * 4;
            m = v0.x; a = b0;
            if (v0.y > m) { m = v0.y; a = b0 + 1; }
            if (v0.z > m) { m = v0.z; a = b0 + 2; }
            if (v0.w > m) { m = v0.w; a = b0 + 3; }
            const int b1 = 16 + b0;
            if (v1.x > m) { m = v1.x; a = b1; }
            if (v1.y > m) { m = v1.y; a = b1 + 1; }
            if (v1.z > m) { m = v1.z; a = b1 + 2; }
            if (v1.w > m) { m = v1.w; a = b1 + 3; }
            const int b2 = 32 + b0;
            if (v2.x > m) { m = v2.x; a = b2; }
            if (v2.y > m) { m = v2.y; a = b2 + 1; }
            if (v2.z > m) { m = v2.z; a = b2 + 2; }
            if (v2.w > m) { m = v2.w; a = b2 + 3; }
            const int b3 = 48 + b0;
            if (v3.x > m) { m = v3.x; a = b3; }
            if (v3.y > m) { m = v3.y; a = b3 + 1; }
            if (v3.z > m) { m = v3.z; a = b3 + 2; }
            if (v3.w > m) { m = v3.w; a = b3 + 3; }
        }

        // 2-step butterfly across the 4 lanes of this row (max, first-argmax)
        float conf = valid ? m : -1.f;
        int   pred = a;
        {
            float om = __shfl_xor(conf, 1, 64);
            int   oa = __shfl_xor(pred, 1, 64);
            if (om > conf || (om == conf && oa < pred)) { conf = om; pred = oa; }
            om = __shfl_xor(conf, 2, 64);
            oa = __shfl_xor(pred, 2, 64);
            if (om > conf || (om == conf && oa < pred)) { conf = om; pred = oa; }
        }

        if (l4 == 0 && valid && conf > 0.f) {
            const float acc = (pred == lab) ? 1.f : 0.f;
            int bin = (int)ceilf(conf * 15.f) - 1;   // (lower, upper] bins
            bin = min(max(bin, 0), N_BINS - 1);
            if (bin == 14)      { c14 += conf; a14 += acc; n14 += 1.f; }
            else if (bin == 13) { c13 += conf; a13 += acc; n13 += 1.f; }
            else {                                    // ~1e-4 of rows
                atomicAdd(&s_bins[bin],              conf);
                atomicAdd(&s_bins[N_BINS + bin],     acc);
                atomicAdd(&s_bins[2 * N_BINS + bin], 1.f);
            }
        }
    }

    // privates are nonzero on lanes with l4==0 (16 lanes) → butterfly to lane 0
    #pragma unroll
    for (int off = 4; off <= 32; off <<= 1) {
        c14 += __shfl_xor(c14, off, 64);
        a14 += __shfl_xor(a14, off, 64);
        n14 += __shfl_xor(n14, off, 64);
        c13 += __shfl_xor(c13, off, 64);
        a13 += __shfl_xor(a13, off, 64);
        n13 += __shfl_xor(n13, off, 64);
    }
    if (lane == 0) {
        atomicAdd(&s_bins[14],              c14);
        atomicAdd(&s_bins[N_BINS + 14],     a14);
        atomicAdd(&s_bins[2 * N_BINS + 14], n14);
        atomicAdd(&s_bins[13],              c13);
        atomicAdd(&s_bins[N_BINS + 13],     a13);
        atomicAdd(&s_bins[2 * N_BINS + 13], n13);
    }
    __syncthreads();
    // flush only nonzero bins → ~6 instead of 45 global atomics per block
    if (tid < 3 * N_BINS && s_bins[tid] != 0.f) atomicAdd(&gbins[tid], s_bins[tid]);
}

__global__ void ece_final(const float* __restrict__ gbins,
                          float* __restrict__ out, int N) {
    if (threadIdx.x == 0 && blockIdx.x == 0) {
        float ece = 0.f;
        const float invN = 1.f / (float)N;
        for (int b = 0; b < N_BINS; b++) {
            const float sc = gbins[b];
            const float sa = gbins[N_BINS + b];
            const float cn = gbins[2 * N_BINS + b];
            if (cn > 0.f) {
                const float avg_conf = sc / cn;
                const float avg_acc  = sa / cn;
                ece += fabsf(avg_conf - avg_acc) * (cn * invN);
            }
        }
        out[0] = ece;
    }
}

extern "C" void kernel_launch(void* const* d_in, const int* in_sizes, int n_in,
                              void* d_out, int out_size, void* d_ws, size_t ws_size,
                              hipStream_t stream) {
    const float* probs  = (const float*)d_in[0];
    const int*   labels = (const int*)d_in[1];
    float* gbins = (float*)d_ws;
    float* out   = (float*)d_out;

    const int N = in_sizes[1];   // number of rows (labels count)

    hipMemsetAsync(d_ws, 0, 3 * N_BINS * sizeof(float), stream);

    const int threads = 256;     // 4 waves/block
    const int blocks  = 2048;    // 8192 waves = 32 waves/CU
    ece_main<<<blocks, threads, 0, stream>>>(probs, labels, gbins, N);
    ece_final<<<1, 64, 0, stream>>>(gbins, out, N);
}

// Round 2
// 644.724 us; speedup vs baseline: 1.0310x; 1.0125x over previous
//
#include <hip/hip_runtime.h>

#define N_BINS 15

typedef float f32x4 __attribute__((ext_vector_type(4)));

__device__ __forceinline__ f32x4 ntld(const void* p) {
    return __builtin_nontemporal_load((const f32x4*)p);
}

// d_ws layout: [0..14] sum_conf, [15..29] sum_acc, [30..44] count  (floats)

__global__ __launch_bounds__(256) void ece_main(const float* __restrict__ probs,
                                                const int* __restrict__ labels,
                                                float* __restrict__ gbins, int N) {
    __shared__ float s_bins[3 * N_BINS];
    const int tid = threadIdx.x;
    if (tid < 3 * N_BINS) s_bins[tid] = 0.f;
    __syncthreads();

    const int lane = tid & 63;
    const int wave = tid >> 6;
    const int l4   = lane & 3;    // which 16B sub-chunk of each 64B chunk this lane reads
    const int rsub = lane >> 2;   // which of the wave's 16 rows (per group) this lane helps
    const int wavesPerBlock = blockDim.x >> 6;

    // private accumulators (bin14 ~98.8% of rows, bin13 ~1.2%)
    float c14 = 0.f, a14 = 0.f, n14 = 0.f;
    float c13 = 0.f, a13 = 0.f, n13 = 0.f;

    const unsigned Nu = (unsigned)N;
    const unsigned totalWaves = (unsigned)gridDim.x * wavesPerBlock;
    const unsigned stride = totalWaves * 32u;              // 32 rows per wave per iter
    unsigned rbase = ((unsigned)blockIdx.x * wavesPerBlock + wave) * 32u;
    const char* pb = (const char*)probs;

    // process one 16-row group held in registers; rows are lane-parallel (4 lanes/row)
    auto doGroup = [&](f32x4 v0, f32x4 v1, f32x4 v2, f32x4 v3, int lab, bool valid) {
        // max over this lane's 16 elements — pure max tree (fuses to v_max3)
        const float m0 = fmaxf(fmaxf(v0.x, v0.y), fmaxf(v0.z, v0.w));
        const float m1 = fmaxf(fmaxf(v1.x, v1.y), fmaxf(v1.z, v1.w));
        const float m2 = fmaxf(fmaxf(v2.x, v2.y), fmaxf(v2.z, v2.w));
        const float m3 = fmaxf(fmaxf(v3.x, v3.y), fmaxf(v3.z, v3.w));
        const float m  = fmaxf(fmaxf(m0, m1), fmaxf(m2, m3));

        // value at the label column (no argmax needed: acc = (probs[row][lab] == max))
        // lane l4 owns cols {16c + 4*l4 + k}; owner of lab = (lab>>2)&3, chunk = lab>>4, elem = lab&3
        const int c2 = (lab >> 4) & 3;
        const int k2 = lab & 3;
        const int ow = (lab >> 2) & 3;
        const f32x4 cc = (c2 & 2) ? ((c2 & 1) ? v3 : v2) : ((c2 & 1) ? v1 : v0);
        const float e = (k2 & 2) ? ((k2 & 1) ? cc.w : cc.z)
                                 : ((k2 & 1) ? cc.y : cc.x);

        float conf = valid ? m : -1.f;
        float lv   = (valid && ow == l4) ? e : -1.f;

        // 2-step butterfly across the row's 4 lanes: max for both conf and label-value
        #pragma unroll
        for (int off = 1; off <= 2; off <<= 1) {
            conf = fmaxf(conf, __shfl_xor(conf, off, 64));
            lv   = fmaxf(lv,   __shfl_xor(lv,   off, 64));
        }

        if (l4 == 0 && valid && conf > 0.f) {
            const float acc = (lv == conf) ? 1.f : 0.f;
            int bin = (int)ceilf(conf * 15.f) - 1;          // (lower, upper] bins
            bin = min(max(bin, 0), N_BINS - 1);
            if (bin == 14)      { c14 += conf; a14 += acc; n14 += 1.f; }
            else if (bin == 13) { c13 += conf; a13 += acc; n13 += 1.f; }
            else {                                           // ~1e-4 of rows
                atomicAdd(&s_bins[bin],              conf);
                atomicAdd(&s_bins[N_BINS + bin],     acc);
                atomicAdd(&s_bins[2 * N_BINS + bin], 1.f);
            }
        }
    };

    for (; rbase < Nu; rbase += stride) {                   // wave-uniform bound
        const unsigned rowA = rbase + rsub;
        const unsigned rowB = rowA + 16u;
        const bool vA = rowA < Nu;
        const bool vB = rowB < Nu;
        const unsigned rAc = vA ? rowA : (Nu - 1u);         // clamp: loads always safe
        const unsigned rBc = vB ? rowB : (Nu - 1u);

        // lane covers bytes rowX*256 + l4*16 + {0,64,128,192}; for each chunk, lanes
        // 0..3 cover one contiguous 64B line of their row → fully-consumed lines.
        const char* pA = pb + (rAc * 256u + (unsigned)l4 * 16u);
        const char* pB = pb + (rBc * 256u + (unsigned)l4 * 16u);

        // 8 independent non-temporal 16B loads issued back-to-back (max MLP;
        // no-allocate avoids evicting the 2GB of dirty poison the fill left in L2/L3)
        const f32x4 a0 = ntld(pA);
        const f32x4 a1 = ntld(pA + 64);
        const f32x4 a2 = ntld(pA + 128);
        const f32x4 a3 = ntld(pA + 192);
        const f32x4 b0 = ntld(pB);
        const f32x4 b1 = ntld(pB + 64);
        const f32x4 b2 = ntld(pB + 128);
        const f32x4 b3 = ntld(pB + 192);
        const int labA = labels[rAc];
        const int labB = labels[rBc];

        doGroup(a0, a1, a2, a3, labA, vA);
        doGroup(b0, b1, b2, b3, labB, vB);
    }

    // privates are nonzero only on l4==0 lanes (0,4,...,60) → butterfly to lane 0
    #pragma unroll
    for (int off = 4; off <= 32; off <<= 1) {
        c14 += __shfl_xor(c14, off, 64);
        a14 += __shfl_xor(a14, off, 64);
        n14 += __shfl_xor(n14, off, 64);
        c13 += __shfl_xor(c13, off, 64);
        a13 += __shfl_xor(a13, off, 64);
        n13 += __shfl_xor(n13, off, 64);
    }
    if (lane == 0) {
        atomicAdd(&s_bins[14],              c14);
        atomicAdd(&s_bins[N_BINS + 14],     a14);
        atomicAdd(&s_bins[2 * N_BINS + 14], n14);
        atomicAdd(&s_bins[13],              c13);
        atomicAdd(&s_bins[N_BINS + 13],     a13);
        atomicAdd(&s_bins[2 * N_BINS + 13], n13);
    }
    __syncthreads();
    // flush only nonzero bins → ~6 instead of 45 global atomics per block
    if (tid < 3 * N_BINS && s_bins[tid] != 0.f) atomicAdd(&gbins[tid], s_bins[tid]);
}

__global__ void ece_final(const float* __restrict__ gbins,
                          float* __restrict__ out, int N) {
    if (threadIdx.x == 0 && blockIdx.x == 0) {
        float ece = 0.f;
        const float invN = 1.f / (float)N;
        for (int b = 0; b < N_BINS; b++) {
            const float sc = gbins[b];
            const float sa = gbins[N_BINS + b];
            const float cn = gbins[2 * N_BINS + b];
            if (cn > 0.f) {
                const float avg_conf = sc / cn;
                const float avg_acc  = sa / cn;
                ece += fabsf(avg_conf - avg_acc) * (cn * invN);
            }
        }
        out[0] = ece;
    }
}

extern "C" void kernel_launch(void* const* d_in, const int* in_sizes, int n_in,
                              void* d_out, int out_size, void* d_ws, size_t ws_size,
                              hipStream_t stream) {
    const float* probs  = (const float*)d_in[0];
    const int*   labels = (const int*)d_in[1];
    float* gbins = (float*)d_ws;
    float* out   = (float*)d_out;

    const int N = in_sizes[1];   // number of rows (labels count)

    hipMemsetAsync(d_ws, 0, 3 * N_BINS * sizeof(float), stream);

    const int threads = 256;     // 4 waves/block
    const int blocks  = 2048;    // 8192 waves
    ece_main<<<blocks, threads, 0, stream>>>(probs, labels, gbins, N);
    ece_final<<<1, 64, 0, stream>>>(gbins, out, N);
}